// Round 7
// baseline (560.350 us; speedup 1.0000x reference)
//
#include <hip/hip_runtime.h>
#include <math.h>

#define B_   16
#define L_   8192
#define D_   64
#define R_   4
#define NB_  128   // n_buckets = L/64
#define NH_  64    // rand_matrix last dim = n_buckets/2

typedef float v2f __attribute__((ext_vector_type(2)));

// DPP helpers: quad-local (4-lane) broadcast / butterfly — pure VALU, no LDS pipe.
__device__ __forceinline__ float dpp_xor1(float x) {
    return __int_as_float(__builtin_amdgcn_mov_dpp(__float_as_int(x), 0xB1, 0xf, 0xf, true)); // quad_perm(1,0,3,2)
}
__device__ __forceinline__ float dpp_xor2(float x) {
    return __int_as_float(__builtin_amdgcn_mov_dpp(__float_as_int(x), 0x4E, 0xf, 0xf, true)); // quad_perm(2,3,0,1)
}
__device__ __forceinline__ float quad_bcast0(float x) {
    return __int_as_float(__builtin_amdgcn_mov_dpp(__float_as_int(x), 0x00, 0xf, 0xf, true));
}
__device__ __forceinline__ float quad_bcast1(float x) {
    return __int_as_float(__builtin_amdgcn_mov_dpp(__float_as_int(x), 0x55, 0xf, 0xf, true));
}
__device__ __forceinline__ float quad_bcast2(float x) {
    return __int_as_float(__builtin_amdgcn_mov_dpp(__float_as_int(x), 0xAA, 0xf, 0xf, true));
}
__device__ __forceinline__ float quad_bcast3(float x) {
    return __int_as_float(__builtin_amdgcn_mov_dpp(__float_as_int(x), 0xFF, 0xf, 0xf, true));
}

// ---------------- K1: normalize rand_matrix columns over d (fp64), store [b][r][n][d]
// R17: also emits an fp32 copy rmf (bit-identical to (float)rmn) so k_hash stages
// half the bytes and skips per-block fp64->fp32 converts.
__global__ __launch_bounds__(64) void k_rmnorm(const float* __restrict__ rm, double* __restrict__ rmn,
                                               float* __restrict__ rmf) {
    int b = blockIdx.x >> 2, r = blockIdx.x & 3;
    int n = threadIdx.x;
    float v[D_];
    double ss = 0.0;
    #pragma unroll
    for (int d = 0; d < D_; ++d) {
        float f = rm[((size_t)(b * D_ + d) * R_ + r) * NH_ + n];
        v[d] = f;
        ss += (double)f * (double)f;
    }
    double nrm = sqrt(ss); if (nrm < 1e-12) nrm = 1e-12;
    double inv = 1.0 / nrm;
    double* o  = rmn + ((size_t)(b * R_ + r) * NH_ + n) * D_;
    float*  of = rmf + ((size_t)(b * R_ + r) * NH_ + n) * D_;
    #pragma unroll
    for (int d = 0; d < D_; ++d) {
        double dv = (double)v[d] * inv;
        o[d] = dv;
        of[d] = (float)dv;   // identical to the old per-block (float)rmn conversion
    }
}

// ---------------- K2: LSH hash — packed-fp32 argmax with top-2 margin test, fp64 re-check
// for near-tie lanes. fp32 dot error bound ~1.4e-6*||q||; margin 1.2e-5*||q|| = 8x safety.
// R17: TWO queries per thread — each rms row read feeds both queries' FMAs, halving
// the per-CU LDS issue count (the k_hash bottleneck: every thread re-read the same
// 16KB table, 1024 broadcast b128 reads/thread). Per-query arithmetic order is
// unchanged -> hashes bit-identical. Stages from fp32 rmf (half the staging bytes).
__global__ __launch_bounds__(256, 2) void k_hash(const float* __restrict__ q, const double* __restrict__ rmn,
                                                 const float* __restrict__ rmf,
                                                 float* __restrict__ rn, int* __restrict__ h) {
    __shared__ float rms[NH_ * D_]; // 16 KB
    int b = blockIdx.z, r = blockIdx.y;
    int t = threadIdx.x;
    int l0 = blockIdx.x * 512 + t;
    int l1 = l0 + 256;
    const double* src = rmn + (size_t)(b * R_ + r) * NH_ * D_;
    const float* srcf = rmf + (size_t)(b * R_ + r) * NH_ * D_;
    for (int i = t * 4; i < NH_ * D_; i += 1024)
        *(float4*)&rms[i] = *(const float4*)&srcf[i];
    const float* qp0 = q + ((size_t)b * L_ + l0) * D_;
    const float* qp1 = q + ((size_t)b * L_ + l1) * D_;
    v2f qa[D_ / 2], qb[D_ / 2];
    double ssa = 0.0, ssb = 0.0;
    #pragma unroll
    for (int d = 0; d < D_; d += 4) {
        float4 f = *(const float4*)(qp0 + d);
        qa[d >> 1]       = (v2f){f.x, f.y};
        qa[(d >> 1) + 1] = (v2f){f.z, f.w};
        ssa += (double)f.x * f.x + (double)f.y * f.y + (double)f.z * f.z + (double)f.w * f.w;
        float4 g = *(const float4*)(qp1 + d);
        qb[d >> 1]       = (v2f){g.x, g.y};
        qb[(d >> 1) + 1] = (v2f){g.z, g.w};
        ssb += (double)g.x * g.x + (double)g.y * g.y + (double)g.z * g.z + (double)g.w * g.w;
    }
    __syncthreads();
    float besta = -1.0e30f, seconda = -1.0e30f; int bia = 0;
    float bestb = -1.0e30f, secondb = -1.0e30f; int bib = 0;
    for (int n = 0; n < NH_; ++n) {
        const float* kp = &rms[n * D_];
        v2f a0 = (v2f){0.f, 0.f}, a1 = a0, c0 = a0, c1 = a0;
        #pragma unroll
        for (int d = 0; d < D_; d += 4) {
            float4 kk = *(const float4*)(kp + d);
            v2f kA = (v2f){kk.x, kk.y}, kB = (v2f){kk.z, kk.w};
            int i2 = d >> 1;
            a0 = __builtin_elementwise_fma(qa[i2],     kA, a0);
            a1 = __builtin_elementwise_fma(qa[i2 + 1], kB, a1);
            c0 = __builtin_elementwise_fma(qb[i2],     kA, c0);
            c1 = __builtin_elementwise_fma(qb[i2 + 1], kB, c1);
        }
        float sa = (a0.x + a0.y) + (a1.x + a1.y);
        if (sa > besta)        { seconda = besta; besta = sa; bia = n; }
        else if (sa > seconda)   seconda = sa;
        float nsa = -sa;
        if (nsa > besta)       { seconda = besta; besta = nsa; bia = n + NH_; }
        else if (nsa > seconda)  seconda = nsa;
        float sb = (c0.x + c0.y) + (c1.x + c1.y);
        if (sb > bestb)        { secondb = bestb; bestb = sb; bib = n; }
        else if (sb > secondb)   secondb = sb;
        float nsb = -sb;
        if (nsb > bestb)       { secondb = bestb; bestb = nsb; bib = n + NH_; }
        else if (nsb > secondb)  secondb = nsb;
    }
    float qna = (float)sqrt(ssa);
    if (besta - seconda < 1.2e-5f * qna + 1.0e-7f) {
        double bestd = -1.0e300; bia = 0;
        for (int n = 0; n < NH_; ++n) {
            const double* kp = src + n * D_;
            double a0 = 0, a1 = 0, a2 = 0, a3 = 0;
            #pragma unroll
            for (int d = 0; d < D_; d += 4) {
                a0 = fma((double)qa[d >> 1].x,       kp[d],     a0);
                a1 = fma((double)qa[d >> 1].y,       kp[d + 1], a1);
                a2 = fma((double)qa[(d >> 1) + 1].x, kp[d + 2], a2);
                a3 = fma((double)qa[(d >> 1) + 1].y, kp[d + 3], a3);
            }
            double s = (a0 + a1) + (a2 + a3);
            if (s > bestd)  { bestd = s;  bia = n; }
            if (-s > bestd) { bestd = -s; bia = n + NH_; }
        }
    }
    float qnb = (float)sqrt(ssb);
    if (bestb - secondb < 1.2e-5f * qnb + 1.0e-7f) {
        double bestd = -1.0e300; bib = 0;
        for (int n = 0; n < NH_; ++n) {
            const double* kp = src + n * D_;
            double a0 = 0, a1 = 0, a2 = 0, a3 = 0;
            #pragma unroll
            for (int d = 0; d < D_; d += 4) {
                a0 = fma((double)qb[d >> 1].x,       kp[d],     a0);
                a1 = fma((double)qb[d >> 1].y,       kp[d + 1], a1);
                a2 = fma((double)qb[(d >> 1) + 1].x, kp[d + 2], a2);
                a3 = fma((double)qb[(d >> 1) + 1].y, kp[d + 3], a3);
            }
            double s = (a0 + a1) + (a2 + a3);
            if (s > bestd)  { bestd = s;  bib = n; }
            if (-s > bestd) { bestd = -s; bib = n + NH_; }
        }
    }
    h[(size_t)(b * R_ + r) * L_ + l0] = bia;
    h[(size_t)(b * R_ + r) * L_ + l1] = bib;
    if (r == 0) {
        double na = sqrt(ssa); if (na < 1e-12) na = 1e-12;
        rn[(size_t)b * L_ + l0] = (float)(1.0 / na);
        double nb = sqrt(ssb); if (nb < 1e-12) nb = 1e-12;
        rn[(size_t)b * L_ + l1] = (float)(1.0 / nb);
    }
}

// ---------------- K3: stable counting sort by bucket per (b,r).
// 256 threads/block; counter matrix [bucket][thread] stride-257 padded.
// Emits packed per-position records rec[pos] = {l | bucket<<16, rn[l] raw bits}.
__global__ __launch_bounds__(256) void k_sort(const int* __restrict__ h, const float* __restrict__ rn,
                                              int* __restrict__ iv, int2* __restrict__ rec) {
    __shared__ unsigned int cnt[NB_ * 257];  // 128.5 KB (fits 160 KB LDS)
    __shared__ unsigned int wsum[4];
    int br = blockIdx.x;
    const int* hh = h + (size_t)br * L_;
    const float* rnb = rn + (size_t)(br >> 2) * L_;
    int t = threadIdx.x;
    for (int i = t; i < NB_ * 257; i += 256) cnt[i] = 0;
    __syncthreads();
    int base = t * 32;                      // each thread owns 32 consecutive l
    for (int i = 0; i < 32; ++i) { int bk = hh[base + i]; cnt[bk * 257 + t]++; }
    __syncthreads();
    // exclusive scan over the flattened (bucket-major, thread-minor) 32768 cells.
    int fb = t * 128;                        // this thread's contiguous logical range
    unsigned int local = 0;
    for (int i = 0; i < 128; ++i) { unsigned g = fb + i; local += cnt[g + (g >> 8)]; }
    unsigned int v = local;
    #pragma unroll
    for (int off = 1; off < 64; off <<= 1) {
        unsigned int u = __shfl_up(v, off);
        if ((t & 63) >= off) v += u;
    }
    if ((t & 63) == 63) wsum[t >> 6] = v;
    __syncthreads();
    unsigned int wbase = 0;
    for (int w = 0; w < (t >> 6); ++w) wbase += wsum[w];
    unsigned int run = wbase + v - local;    // exclusive base for this thread's cells
    for (int i = 0; i < 128; ++i) {
        unsigned g = fb + i;
        unsigned int c0 = cnt[g + (g >> 8)];
        cnt[g + (g >> 8)] = run; run += c0;
    }
    __syncthreads();
    int* ivp = iv + (size_t)br * L_;
    int2* rp = rec + (size_t)br * L_;
    for (int i = 0; i < 32; ++i) {
        int l = base + i; int bk = hh[l];
        unsigned int pos = cnt[bk * 257 + t]++;
        ivp[l] = (int)pos;
        rp[pos] = make_int2(l | (bk << 16), __float_as_int(rnb[l]));
    }
}

// ---------------- K4: fused flash pass — QK^T, static-max softmax, PV in one sweep.
// R16 structure (R0 champion + bucket-range skipping) + R17 PREDICATED STAGING:
// lanes staging a dead row (bucket outside [minbk,maxbk]) skip the K/V global
// loads and LDS writes entirely — those j's are skipped in compute, so the stale
// LDS is never read. Cuts residual over-fetch for partially-alive stages.
// omode: 0 = store O/sum + lse, contrib indexed [(b*R+r)*L + pos] (tierA)
//        1 = same but contrib indexed [b*L + pos] (tierB per-round slice)
//        2 = lse only (tierC pass 1)
//        3 = atomic w-weighted add into out (tierC pass 2; needs gm/gs)
__global__ __launch_bounds__(128, 2) void k_flash(const float* __restrict__ q, const float* __restrict__ val,
                                                  const int2* __restrict__ rec, float* __restrict__ lse,
                                                  const float* __restrict__ gm, const float* __restrict__ gs,
                                                  float* __restrict__ out, float* __restrict__ contrib,
                                                  int r_fixed, int omode) {
    __shared__ float kt[2][16 * 80];   // per-wave: 16 rows x 4 slices @ stride 20 words
    __shared__ float vt[2][16 * 80];
    __shared__ int2  krc[2][16];       // {l|bk<<16, rn bits} per key
    int w   = threadIdx.x >> 6;
    int tid = threadIdx.x & 63;
    int c = blockIdx.x * 2 + w, b = blockIdx.z;
    int r = (r_fixed < 0) ? (int)blockIdx.y : r_fixed;
    size_t sbase = (size_t)(b * R_ + r) * L_;
    const int2* recs = rec + sbase;
    const float* qb = q   + (size_t)b * L_ * D_;
    const float* vb = val + (size_t)b * L_ * D_;
    int loadv = (omode != 2);
    int h = tid & 3;
    int posq = c * 64 + (tid >> 2) * 4;           // first query of this lane's quad
    int2 rown = recs[posq + h];
    int own_w0 = rown.x;
    int own_bk = own_w0 & 0xFFFF0000;
    float m_own = 0.125f / __int_as_float(rown.y);   // == ||q_own||/8
    // wave query-bucket range (positions sorted by bucket -> first/last suffice)
    int minbk = __builtin_amdgcn_readfirstlane(recs[c * 64].x) & 0xFFFF0000;
    int maxbk = __builtin_amdgcn_readfirstlane(recs[c * 64 + 63].x) & 0xFFFF0000;
    int mls[4];
    #pragma unroll
    for (int qq = 0; qq < 4; ++qq) mls[qq] = recs[posq + qq].x & 0xFFFF;
    int ownpos = posq + h;
    v2f qv2[4][8];
    #pragma unroll
    for (int qq = 0; qq < 4; ++qq) {
        const float* qp = qb + (size_t)mls[qq] * D_ + h * 16;
        #pragma unroll
        for (int i = 0; i < 16; i += 4) {
            float4 f = *(const float4*)(qp + i);
            qv2[qq][i >> 1]       = (v2f){f.x, f.y};
            qv2[qq][(i >> 1) + 1] = (v2f){f.z, f.w};
        }
    }
    float ps[4] = {0.0f, 0.0f, 0.0f, 0.0f};
    v2f acc2[4][8];
    #pragma unroll
    for (int qq = 0; qq < 4; ++qq)
        #pragma unroll
        for (int i = 0; i < 8; ++i) acc2[qq][i] = (v2f){0.0f, 0.0f};

    #pragma unroll 1
    for (int s = 0; s < 8; ++s) {   // 8 stages of 16 keys: prev chunk (4) then current (4)
        int ck = ((c + NB_ - 1 + (s >> 2)) & (NB_ - 1)) * 64 + (s & 3) * 16;
        // stage-level skip: keys sorted within stage -> range test vs query buckets.
        // Dead stage contributes exactly 0 to ps/acc (expf(-1e9-m)==0.0f) -> exact.
        int sfir = __builtin_amdgcn_readfirstlane(recs[ck].x) & 0xFFFF0000;
        int slas = __builtin_amdgcn_readfirstlane(recs[ck + 15].x) & 0xFFFF0000;
        if (slas < minbk || sfir > maxbk) continue;
        {
            int rw = tid >> 2, cc = tid & 3;
            int rrec = recs[ck + rw].x;
            int rbk = rrec & 0xFFFF0000;
            if (rbk >= minbk && rbk <= maxbk) {   // predicated: dead rows never staged
                int kl = rrec & 0xFFFF;
                const float* kp = qb + (size_t)kl * D_ + cc * 16;
                float* kd = &kt[w][rw * 80 + cc * 20];
                #pragma unroll
                for (int i = 0; i < 16; i += 4) *(float4*)(kd + i) = *(const float4*)(kp + i);
                if (loadv) {
                    const float* vp = vb + (size_t)kl * D_ + cc * 16;
                    float* vd = &vt[w][rw * 80 + cc * 20];
                    #pragma unroll
                    for (int i = 0; i < 16; i += 4) *(float4*)(vd + i) = *(const float4*)(vp + i);
                }
            }
            if (tid < 16) krc[w][tid] = recs[ck + tid];
        }
        // no barrier: single-wave producer/consumer, lgkmcnt ordering suffices (R6)
        #pragma unroll
        for (int j = 0; j < 16; ++j) {
            int2 kv = krc[w][j];
            // per-key skip (uniform branch): bucket outside wave range -> exact zero
            int bkj = __builtin_amdgcn_readfirstlane(kv.x) & 0xFFFF0000;
            if (bkj < minbk || bkj > maxbk) continue;
            const float* kpj = &kt[w][j * 80 + h * 20];
            v2f a0 = (v2f){0.f, 0.f}, a1 = a0, a2 = a0, a3 = a0;
            #pragma unroll
            for (int i = 0; i < 16; i += 4) {
                float4 kk = *(const float4*)(kpj + i);
                v2f kA = (v2f){kk.x, kk.y}, kB = (v2f){kk.z, kk.w};
                int i2 = i >> 1;
                a0 = __builtin_elementwise_fma(qv2[0][i2], kA, a0);
                a0 = __builtin_elementwise_fma(qv2[0][i2 + 1], kB, a0);
                a1 = __builtin_elementwise_fma(qv2[1][i2], kA, a1);
                a1 = __builtin_elementwise_fma(qv2[1][i2 + 1], kB, a1);
                a2 = __builtin_elementwise_fma(qv2[2][i2], kA, a2);
                a2 = __builtin_elementwise_fma(qv2[2][i2 + 1], kB, a2);
                a3 = __builtin_elementwise_fma(qv2[3][i2], kA, a3);
                a3 = __builtin_elementwise_fma(qv2[3][i2 + 1], kB, a3);
            }
            float p0 = a0.x + a0.y, p1 = a1.x + a1.y, p2 = a2.x + a2.y, p3 = a3.x + a3.y;
            // 4x4 transpose-reduce across the quad: lane h ends with query h's full dot
            bool b0 = (h & 1), b1 = (h & 2) != 0;
            float u0 = b0 ? p1 : p0;
            float t0 = b0 ? p0 : p1;
            u0 += dpp_xor1(t0);
            float u2 = b0 ? p3 : p2;
            float t2 = b0 ? p2 : p3;
            u2 += dpp_xor1(t2);
            float dot = b1 ? u2 : u0;
            float t3 = b1 ? u0 : u2;
            dot += dpp_xor2(t3);
            float skr = __int_as_float(kv.y) * 0.125f;       // rn_k * 0.125
            float sc = dot * skr;
            sc = (own_bk == (kv.x & 0xFFFF0000)) ? sc : -1.0e9f;  // cross-bucket mask
            if (own_w0 == kv.x) sc = -1.0e5f;          // self mask (overrides, as in ref)
            float p = __expf(sc - m_own);              // static max: no rescaling ever
            ps[j & 3] += p;
            if (loadv) {
                v2f P0 = (v2f){quad_bcast0(p), quad_bcast0(p)};
                v2f P1 = (v2f){quad_bcast1(p), quad_bcast1(p)};
                v2f P2 = (v2f){quad_bcast2(p), quad_bcast2(p)};
                v2f P3 = (v2f){quad_bcast3(p), quad_bcast3(p)};
                const float* vpj = &vt[w][j * 80 + h * 20];
                float4 vv0 = *(const float4*)(vpj + 0);
                float4 vv1 = *(const float4*)(vpj + 4);
                float4 vv2 = *(const float4*)(vpj + 8);
                float4 vv3 = *(const float4*)(vpj + 12);
                v2f vAa = (v2f){vv0.x, vv0.y}, vAb = (v2f){vv0.z, vv0.w};
                v2f vAc = (v2f){vv1.x, vv1.y}, vAd = (v2f){vv1.z, vv1.w};
                v2f vAe = (v2f){vv2.x, vv2.y}, vAf = (v2f){vv2.z, vv2.w};
                v2f vAg = (v2f){vv3.x, vv3.y}, vAh = (v2f){vv3.z, vv3.w};
                acc2[0][0] = __builtin_elementwise_fma(P0, vAa, acc2[0][0]);
                acc2[0][1] = __builtin_elementwise_fma(P0, vAb, acc2[0][1]);
                acc2[0][2] = __builtin_elementwise_fma(P0, vAc, acc2[0][2]);
                acc2[0][3] = __builtin_elementwise_fma(P0, vAd, acc2[0][3]);
                acc2[0][4] = __builtin_elementwise_fma(P0, vAe, acc2[0][4]);
                acc2[0][5] = __builtin_elementwise_fma(P0, vAf, acc2[0][5]);
                acc2[0][6] = __builtin_elementwise_fma(P0, vAg, acc2[0][6]);
                acc2[0][7] = __builtin_elementwise_fma(P0, vAh, acc2[0][7]);
                acc2[1][0] = __builtin_elementwise_fma(P1, vAa, acc2[1][0]);
                acc2[1][1] = __builtin_elementwise_fma(P1, vAb, acc2[1][1]);
                acc2[1][2] = __builtin_elementwise_fma(P1, vAc, acc2[1][2]);
                acc2[1][3] = __builtin_elementwise_fma(P1, vAd, acc2[1][3]);
                acc2[1][4] = __builtin_elementwise_fma(P1, vAe, acc2[1][4]);
                acc2[1][5] = __builtin_elementwise_fma(P1, vAf, acc2[1][5]);
                acc2[1][6] = __builtin_elementwise_fma(P1, vAg, acc2[1][6]);
                acc2[1][7] = __builtin_elementwise_fma(P1, vAh, acc2[1][7]);
                acc2[2][0] = __builtin_elementwise_fma(P2, vAa, acc2[2][0]);
                acc2[2][1] = __builtin_elementwise_fma(P2, vAb, acc2[2][1]);
                acc2[2][2] = __builtin_elementwise_fma(P2, vAc, acc2[2][2]);
                acc2[2][3] = __builtin_elementwise_fma(P2, vAd, acc2[2][3]);
                acc2[2][4] = __builtin_elementwise_fma(P2, vAe, acc2[2][4]);
                acc2[2][5] = __builtin_elementwise_fma(P2, vAf, acc2[2][5]);
                acc2[2][6] = __builtin_elementwise_fma(P2, vAg, acc2[2][6]);
                acc2[2][7] = __builtin_elementwise_fma(P2, vAh, acc2[2][7]);
                acc2[3][0] = __builtin_elementwise_fma(P3, vAa, acc2[3][0]);
                acc2[3][1] = __builtin_elementwise_fma(P3, vAb, acc2[3][1]);
                acc2[3][2] = __builtin_elementwise_fma(P3, vAc, acc2[3][2]);
                acc2[3][3] = __builtin_elementwise_fma(P3, vAd, acc2[3][3]);
                acc2[3][4] = __builtin_elementwise_fma(P3, vAe, acc2[3][4]);
                acc2[3][5] = __builtin_elementwise_fma(P3, vAf, acc2[3][5]);
                acc2[3][6] = __builtin_elementwise_fma(P3, vAg, acc2[3][6]);
                acc2[3][7] = __builtin_elementwise_fma(P3, vAh, acc2[3][7]);
            }
        }
    }
    float sum = (ps[0] + ps[1]) + (ps[2] + ps[3]);
    float lse_own, inv_own;
    if (sum > 0.0f) { lse_own = m_own + logf(sum); inv_own = 1.0f / sum; }
    else            { lse_own = -3.0e38f;          inv_own = 0.0f; }   // fully-masked row
    if (omode != 3) lse[sbase + ownpos] = lse_own;
    if (omode == 0 || omode == 1) {
        float ivs[4];
        ivs[0] = quad_bcast0(inv_own); ivs[1] = quad_bcast1(inv_own);
        ivs[2] = quad_bcast2(inv_own); ivs[3] = quad_bcast3(inv_own);
        float* cbase = contrib + ((omode == 0) ? (size_t)(b * R_ + r) * L_ : (size_t)b * L_) * D_;
        #pragma unroll
        for (int qq = 0; qq < 4; ++qq) {
            float* cp = cbase + (size_t)(posq + qq) * D_ + h * 16;
            #pragma unroll
            for (int i = 0; i < 16; i += 4) {
                int i2 = i >> 1;
                float4 o;
                o.x = acc2[qq][i2].x * ivs[qq];     o.y = acc2[qq][i2].y * ivs[qq];
                o.z = acc2[qq][i2 + 1].x * ivs[qq]; o.w = acc2[qq][i2 + 1].y * ivs[qq];
                *(float4*)(cp + i) = o;
            }
        }
    } else if (omode == 3) {
        int brr = b * R_ + r;
        float gmv = gm[brr], gsv = gs[brr];
        float ls4[4], iv4[4];
        ls4[0] = quad_bcast0(lse_own); ls4[1] = quad_bcast1(lse_own);
        ls4[2] = quad_bcast2(lse_own); ls4[3] = quad_bcast3(lse_own);
        iv4[0] = quad_bcast0(inv_own); iv4[1] = quad_bcast1(inv_own);
        iv4[2] = quad_bcast2(inv_own); iv4[3] = quad_bcast3(inv_own);
        #pragma unroll
        for (int qq = 0; qq < 4; ++qq) {
            float wq = __expf(ls4[qq] - gmv) * gsv * iv4[qq];
            float* op = out + ((size_t)b * L_ + mls[qq]) * D_ + h * 16;
            #pragma unroll
            for (int i = 0; i < 8; ++i) {
                unsafeAtomicAdd(op + 2 * i,     wq * acc2[qq][i].x);
                unsafeAtomicAdd(op + 2 * i + 1, wq * acc2[qq][i].y);
            }
        }
    }
}

// ---------------- K5: softmax-over-L normalizers (max + fp64 sum) per (b,r)
__global__ __launch_bounds__(256) void k_wred(const float* __restrict__ lse, float* __restrict__ gm,
                                              float* __restrict__ gs, int r_w) {
    __shared__ float  sm[4];
    __shared__ double sd[4];
    int br = (r_w < 0) ? (int)blockIdx.x : ((int)blockIdx.x * R_ + r_w);
    const float* x = lse + (size_t)br * L_;
    int t = threadIdx.x;
    float mx = -3.0e38f;
    for (int i = t; i < L_; i += 256) mx = fmaxf(mx, x[i]);
    #pragma unroll
    for (int o = 32; o; o >>= 1) mx = fmaxf(mx, __shfl_down(mx, o));
    if ((t & 63) == 0) sm[t >> 6] = mx;
    __syncthreads();
    mx = fmaxf(fmaxf(sm[0], sm[1]), fmaxf(sm[2], sm[3]));
    double s = 0.0;
    for (int i = t; i < L_; i += 256) s += exp((double)x[i] - (double)mx);
    #pragma unroll
    for (int o = 32; o; o >>= 1) s += __shfl_down(s, o);
    if ((t & 63) == 0) sd[t >> 6] = s;
    __syncthreads();
    if (t == 0) { gm[br] = mx; gs[br] = (float)(1.0 / (sd[0] + sd[1] + sd[2] + sd[3])); }
}

// ---------------- K6a: gather all 4 rounds from full contrib, apply w, write out
__global__ __launch_bounds__(256) void k_comb_full(const float* __restrict__ contrib,
                                                   const int* __restrict__ iv,
                                                   const float* __restrict__ lse,
                                                   const float* __restrict__ gm,
                                                   const float* __restrict__ gs,
                                                   float* __restrict__ out) {
    int gid = blockIdx.x * 256 + threadIdx.x;
    int row = gid >> 2;              // b*L + l
    int ch  = (gid & 3) * 16;
    int b = row >> 13, l = row & (L_ - 1);
    float s[16];
    #pragma unroll
    for (int i = 0; i < 16; ++i) s[i] = 0.0f;
    #pragma unroll
    for (int r = 0; r < R_; ++r) {
        int brr = b * R_ + r;
        int pos = iv[(size_t)brr * L_ + l];
        float w = expf(lse[(size_t)brr * L_ + pos] - gm[brr]) * gs[brr];
        const float* cp = contrib + ((size_t)brr * L_ + pos) * D_ + ch;
        #pragma unroll
        for (int i = 0; i < 16; i += 4) {
            float4 f = *(const float4*)(cp + i);
            s[i]   = fmaf(w, f.x, s[i]);   s[i+1] = fmaf(w, f.y, s[i+1]);
            s[i+2] = fmaf(w, f.z, s[i+2]); s[i+3] = fmaf(w, f.w, s[i+3]);
        }
    }
    float* op = out + (size_t)row * D_ + ch;
    #pragma unroll
    for (int i = 0; i < 16; i += 4) {
        float4 o; o.x = s[i]; o.y = s[i+1]; o.z = s[i+2]; o.w = s[i+3];
        *(float4*)(op + i) = o;
    }
}

// ---------------- K6b: gather one round's slice, apply w, accumulate into out
__global__ __launch_bounds__(256) void k_comb_add(const float* __restrict__ contrib,
                                                  const int* __restrict__ iv,
                                                  const float* __restrict__ lse,
                                                  const float* __restrict__ gm,
                                                  const float* __restrict__ gs,
                                                  float* __restrict__ out, int r) {
    int gid = blockIdx.x * 256 + threadIdx.x;
    int row = gid >> 2;              // b*L + l
    int ch  = (gid & 3) * 16;
    int b = row >> 13, l = row & (L_ - 1);
    int brr = b * R_ + r;
    int pos = iv[(size_t)brr * L_ + l];
    float w = expf(lse[(size_t)brr * L_ + pos] - gm[brr]) * gs[brr];
    const float* cp = contrib + ((size_t)b * L_ + pos) * D_ + ch;
    float* op = out + (size_t)row * D_ + ch;
    #pragma unroll
    for (int i = 0; i < 16; i += 4) {
        float4 f = *(const float4*)(cp + i);
        float4 o = *(const float4*)(op + i);
        o.x = fmaf(w, f.x, o.x); o.y = fmaf(w, f.y, o.y);
        o.z = fmaf(w, f.z, o.z); o.w = fmaf(w, f.w, o.w);
        *(float4*)(op + i) = o;
    }
}

// ---------------- workspace layout (bytes)
// rec (int2, 4 MB) OVERLAYS rmn (fp64, 2 MB): rmn is dead after k_hash; rec is
// written by k_sort which runs after k_hash (stream-ordered).
// rmf (fp32, 1 MB) OVERLAYS iv (2 MB): rmf is dead after k_hash; iv is written
// by k_sort which runs after k_hash (stream-ordered).
#define OFF_RMN     0u           // double, 2 MB (k_rmnorm -> k_hash)
#define OFF_REC     0u           // int2,   4 MB (k_sort   -> k_flash), overlays RMN
#define OFF_RN      4194304u     // float,  512 KB
#define OFF_H       4718592u     // int,    2 MB
#define OFF_LSE     6815744u     // float,  2 MB
#define OFF_GM      8912896u
#define OFF_GS      8913152u
#define OFF_INV     8913408u     // int,    2 MB
#define OFF_RMF     8913408u     // float,  1 MB (k_rmnorm -> k_hash), overlays INV
#define OFF_CONTRIB 11010560u
#define CONTRIB_FULL_BYTES  134217728ull   // B*R*L*D*4 = 128 MiB
#define CONTRIB_SLICE_BYTES 33554432ull    // B*L*D*4   =  32 MiB

extern "C" void kernel_launch(void* const* d_in, const int* in_sizes, int n_in,
                              void* d_out, int out_size, void* d_ws, size_t ws_size,
                              hipStream_t stream) {
    const float* q  = (const float*)d_in[0];
    const float* v  = (const float*)d_in[1];
    const float* rm = (const float*)d_in[2];
    float* out = (float*)d_out;
    char* ws = (char*)d_ws;
    double* rmn = (double*)(ws + OFF_RMN);
    int2*   rec = (int2*)(ws + OFF_REC);
    float*  rn  = (float*)(ws + OFF_RN);
    int*    h   = (int*)(ws + OFF_H);
    float*  lse = (float*)(ws + OFF_LSE);
    float*  gm  = (float*)(ws + OFF_GM);
    float*  gs  = (float*)(ws + OFF_GS);
    int*    iv  = (int*)(ws + OFF_INV);
    float*  rmf = (float*)(ws + OFF_RMF);
    float*  contrib = (float*)(ws + OFF_CONTRIB);

    int tierA = (ws_size >= (size_t)OFF_CONTRIB + CONTRIB_FULL_BYTES) ? 1 : 0;
    int tierB = (!tierA && ws_size >= (size_t)OFF_CONTRIB + CONTRIB_SLICE_BYTES) ? 1 : 0;

    hipLaunchKernelGGL(k_rmnorm, dim3(B_ * R_), dim3(64), 0, stream, rm, rmn, rmf);
    hipLaunchKernelGGL(k_hash, dim3(L_ / 512, R_, B_), dim3(256), 0, stream, q, rmn, rmf, rn, h);
    hipLaunchKernelGGL(k_sort, dim3(B_ * R_), dim3(256), 0, stream, h, rn, iv, rec);

    if (tierA) {
        hipLaunchKernelGGL(k_flash, dim3(NB_ / 2, R_, B_), dim3(128), 0, stream, q, v, rec,
                           lse, gm, gs, out, contrib, -1, 0);
        hipLaunchKernelGGL(k_wred, dim3(B_ * R_), dim3(256), 0, stream, lse, gm, gs, -1);
        hipLaunchKernelGGL(k_comb_full, dim3(B_ * L_ * 4 / 256), dim3(256), 0, stream,
                           contrib, iv, lse, gm, gs, out);
    } else if (tierB) {
        hipMemsetAsync(d_out, 0, (size_t)B_ * L_ * D_ * sizeof(float), stream);
        for (int r = 0; r < R_; ++r) {
            hipLaunchKernelGGL(k_flash, dim3(NB_ / 2, 1, B_), dim3(128), 0, stream, q, v, rec,
                               lse, gm, gs, out, contrib, r, 1);
            hipLaunchKernelGGL(k_wred, dim3(B_), dim3(256), 0, stream, lse, gm, gs, r);
            hipLaunchKernelGGL(k_comb_add, dim3(B_ * L_ * 4 / 256), dim3(256), 0, stream,
                               contrib, iv, lse, gm, gs, out, r);
        }
    } else {
        // tier C: two flash passes (lse-only, then atomic w-weighted accumulate)
        hipMemsetAsync(d_out, 0, (size_t)B_ * L_ * D_ * sizeof(float), stream);
        hipLaunchKernelGGL(k_flash, dim3(NB_ / 2, R_, B_), dim3(128), 0, stream, q, v, rec,
                           lse, gm, gs, out, contrib, -1, 2);
        hipLaunchKernelGGL(k_wred, dim3(B_ * R_), dim3(256), 0, stream, lse, gm, gs, -1);
        hipLaunchKernelGGL(k_flash, dim3(NB_ / 2, R_, B_), dim3(128), 0, stream, q, v, rec,
                           lse, gm, gs, out, contrib, -1, 3);
    }
}

// Round 8
// 546.492 us; speedup vs baseline: 1.0254x; 1.0254x over previous
//
#include <hip/hip_runtime.h>
#include <math.h>

#define B_   16
#define L_   8192
#define D_   64
#define R_   4
#define NB_  128   // n_buckets = L/64
#define NH_  64    // rand_matrix last dim = n_buckets/2

typedef float v2f __attribute__((ext_vector_type(2)));

// DPP helpers: quad-local (4-lane) broadcast / butterfly — pure VALU, no LDS pipe.
__device__ __forceinline__ float dpp_xor1(float x) {
    return __int_as_float(__builtin_amdgcn_mov_dpp(__float_as_int(x), 0xB1, 0xf, 0xf, true)); // quad_perm(1,0,3,2)
}
__device__ __forceinline__ float dpp_xor2(float x) {
    return __int_as_float(__builtin_amdgcn_mov_dpp(__float_as_int(x), 0x4E, 0xf, 0xf, true)); // quad_perm(2,3,0,1)
}
__device__ __forceinline__ float quad_bcast0(float x) {
    return __int_as_float(__builtin_amdgcn_mov_dpp(__float_as_int(x), 0x00, 0xf, 0xf, true));
}
__device__ __forceinline__ float quad_bcast1(float x) {
    return __int_as_float(__builtin_amdgcn_mov_dpp(__float_as_int(x), 0x55, 0xf, 0xf, true));
}
__device__ __forceinline__ float quad_bcast2(float x) {
    return __int_as_float(__builtin_amdgcn_mov_dpp(__float_as_int(x), 0xAA, 0xf, 0xf, true));
}
__device__ __forceinline__ float quad_bcast3(float x) {
    return __int_as_float(__builtin_amdgcn_mov_dpp(__float_as_int(x), 0xFF, 0xf, 0xf, true));
}

// ---------------- K1: normalize rand_matrix columns over d (fp64), store [b][r][n][d]
// Also emits an fp32 copy rmf (bit-identical to (float)rmn) so k_hash stages half
// the bytes with float4 loads and skips per-block fp64->fp32 converts.
__global__ __launch_bounds__(64) void k_rmnorm(const float* __restrict__ rm, double* __restrict__ rmn,
                                               float* __restrict__ rmf) {
    int b = blockIdx.x >> 2, r = blockIdx.x & 3;
    int n = threadIdx.x;
    float v[D_];
    double ss = 0.0;
    #pragma unroll
    for (int d = 0; d < D_; ++d) {
        float f = rm[((size_t)(b * D_ + d) * R_ + r) * NH_ + n];
        v[d] = f;
        ss += (double)f * (double)f;
    }
    double nrm = sqrt(ss); if (nrm < 1e-12) nrm = 1e-12;
    double inv = 1.0 / nrm;
    double* o  = rmn + ((size_t)(b * R_ + r) * NH_ + n) * D_;
    float*  of = rmf + ((size_t)(b * R_ + r) * NH_ + n) * D_;
    #pragma unroll
    for (int d = 0; d < D_; ++d) {
        double dv = (double)v[d] * inv;
        o[d] = dv;
        of[d] = (float)dv;   // identical to the old per-block (float)rmn conversion
    }
}

// ---------------- K2: LSH hash — packed-fp32 argmax with top-2 margin test, fp64 re-check
// for near-tie lanes. fp32 dot error bound ~1.4e-6*||q||; margin 1.2e-5*||q|| = 8x safety.
// R18: REVERTED to the proven R16 single-query-per-thread structure (R17's 2-query
// variant spilled under the 128-VGPR cap of __launch_bounds__(256,2): aux +34us).
// Kept one safe improvement: rms staged from fp32 rmf via float4 (half the bytes,
// values bit-identical). Tie path unchanged (reads rmn fp64 from global).
__global__ __launch_bounds__(256) void k_hash(const float* __restrict__ q, const double* __restrict__ rmn,
                                              const float* __restrict__ rmf,
                                              float* __restrict__ rn, int* __restrict__ h) {
    __shared__ float rms[NH_ * D_]; // 16 KB
    int b = blockIdx.z, r = blockIdx.y;
    int l = blockIdx.x * 256 + threadIdx.x;
    const double* src = rmn + (size_t)(b * R_ + r) * NH_ * D_;
    const float* srcf = rmf + (size_t)(b * R_ + r) * NH_ * D_;
    for (int i = threadIdx.x * 4; i < NH_ * D_; i += 1024)
        *(float4*)&rms[i] = *(const float4*)&srcf[i];
    const float* qp = q + ((size_t)b * L_ + l) * D_;
    v2f qv2[D_ / 2];
    double ss = 0.0;
    #pragma unroll
    for (int d = 0; d < D_; d += 4) {
        float4 f = *(const float4*)(qp + d);
        qv2[d >> 1]       = (v2f){f.x, f.y};
        qv2[(d >> 1) + 1] = (v2f){f.z, f.w};
        ss += (double)f.x * f.x + (double)f.y * f.y + (double)f.z * f.z + (double)f.w * f.w;
    }
    __syncthreads();
    float best = -1.0e30f, second = -1.0e30f; int bi = 0;
    for (int n = 0; n < NH_; ++n) {
        const float* kp = &rms[n * D_];
        v2f a0 = (v2f){0.f, 0.f}, a1 = a0;
        #pragma unroll
        for (int d = 0; d < D_; d += 4) {
            float4 kk = *(const float4*)(kp + d);
            a0 = __builtin_elementwise_fma(qv2[d >> 1],       (v2f){kk.x, kk.y}, a0);
            a1 = __builtin_elementwise_fma(qv2[(d >> 1) + 1], (v2f){kk.z, kk.w}, a1);
        }
        float s = (a0.x + a0.y) + (a1.x + a1.y);
        if (s > best)       { second = best; best = s; bi = n; }
        else if (s > second)  second = s;
        float ns = -s;
        if (ns > best)      { second = best; best = ns; bi = n + NH_; }
        else if (ns > second) second = ns;
    }
    float qn = (float)sqrt(ss);
    if (best - second < 1.2e-5f * qn + 1.0e-7f) {
        // near-tie: redo exactly as the proven fp64 path (same values, same order);
        // rmn read from global — lane-uniform addresses, broadcast, L2-resident.
        double bestd = -1.0e300; bi = 0;
        for (int n = 0; n < NH_; ++n) {
            const double* kp = src + n * D_;
            double a0 = 0, a1 = 0, a2 = 0, a3 = 0;
            #pragma unroll
            for (int d = 0; d < D_; d += 4) {
                a0 = fma((double)qv2[d >> 1].x,       kp[d],     a0);
                a1 = fma((double)qv2[d >> 1].y,       kp[d + 1], a1);
                a2 = fma((double)qv2[(d >> 1) + 1].x, kp[d + 2], a2);
                a3 = fma((double)qv2[(d >> 1) + 1].y, kp[d + 3], a3);
            }
            double s = (a0 + a1) + (a2 + a3);
            if (s > bestd)  { bestd = s;  bi = n; }
            if (-s > bestd) { bestd = -s; bi = n + NH_; }
        }
    }
    h[(size_t)(b * R_ + r) * L_ + l] = bi;
    if (r == 0) {
        double nrm = sqrt(ss); if (nrm < 1e-12) nrm = 1e-12;
        rn[(size_t)b * L_ + l] = (float)(1.0 / nrm);
    }
}

// ---------------- K3: stable counting sort by bucket per (b,r).
// 256 threads/block; counter matrix [bucket][thread] stride-257 padded.
// Emits packed per-position records rec[pos] = {l | bucket<<16, rn[l] raw bits}.
__global__ __launch_bounds__(256) void k_sort(const int* __restrict__ h, const float* __restrict__ rn,
                                              int* __restrict__ iv, int2* __restrict__ rec) {
    __shared__ unsigned int cnt[NB_ * 257];  // 128.5 KB (fits 160 KB LDS)
    __shared__ unsigned int wsum[4];
    int br = blockIdx.x;
    const int* hh = h + (size_t)br * L_;
    const float* rnb = rn + (size_t)(br >> 2) * L_;
    int t = threadIdx.x;
    for (int i = t; i < NB_ * 257; i += 256) cnt[i] = 0;
    __syncthreads();
    int base = t * 32;                      // each thread owns 32 consecutive l
    for (int i = 0; i < 32; ++i) { int bk = hh[base + i]; cnt[bk * 257 + t]++; }
    __syncthreads();
    // exclusive scan over the flattened (bucket-major, thread-minor) 32768 cells.
    int fb = t * 128;                        // this thread's contiguous logical range
    unsigned int local = 0;
    for (int i = 0; i < 128; ++i) { unsigned g = fb + i; local += cnt[g + (g >> 8)]; }
    unsigned int v = local;
    #pragma unroll
    for (int off = 1; off < 64; off <<= 1) {
        unsigned int u = __shfl_up(v, off);
        if ((t & 63) >= off) v += u;
    }
    if ((t & 63) == 63) wsum[t >> 6] = v;
    __syncthreads();
    unsigned int wbase = 0;
    for (int w = 0; w < (t >> 6); ++w) wbase += wsum[w];
    unsigned int run = wbase + v - local;    // exclusive base for this thread's cells
    for (int i = 0; i < 128; ++i) {
        unsigned g = fb + i;
        unsigned int c0 = cnt[g + (g >> 8)];
        cnt[g + (g >> 8)] = run; run += c0;
    }
    __syncthreads();
    int* ivp = iv + (size_t)br * L_;
    int2* rp = rec + (size_t)br * L_;
    for (int i = 0; i < 32; ++i) {
        int l = base + i; int bk = hh[l];
        unsigned int pos = cnt[bk * 257 + t]++;
        ivp[l] = (int)pos;
        rp[pos] = make_int2(l | (bk << 16), __float_as_int(rnb[l]));
    }
}

// ---------------- K4: fused flash pass — QK^T, static-max softmax, PV in one sweep.
// R16 structure (R0 champion + bucket-range skipping) + R17 PREDICATED STAGING:
// lanes staging a dead row (bucket outside [minbk,maxbk]) skip the K/V global
// loads and LDS writes entirely — those j's are skipped in compute, so the stale
// LDS is never read. Cuts residual over-fetch for partially-alive stages.
// omode: 0 = store O/sum + lse, contrib indexed [(b*R+r)*L + pos] (tierA)
//        1 = same but contrib indexed [b*L + pos] (tierB per-round slice)
//        2 = lse only (tierC pass 1)
//        3 = atomic w-weighted add into out (tierC pass 2; needs gm/gs)
__global__ __launch_bounds__(128, 2) void k_flash(const float* __restrict__ q, const float* __restrict__ val,
                                                  const int2* __restrict__ rec, float* __restrict__ lse,
                                                  const float* __restrict__ gm, const float* __restrict__ gs,
                                                  float* __restrict__ out, float* __restrict__ contrib,
                                                  int r_fixed, int omode) {
    __shared__ float kt[2][16 * 80];   // per-wave: 16 rows x 4 slices @ stride 20 words
    __shared__ float vt[2][16 * 80];
    __shared__ int2  krc[2][16];       // {l|bk<<16, rn bits} per key
    int w   = threadIdx.x >> 6;
    int tid = threadIdx.x & 63;
    int c = blockIdx.x * 2 + w, b = blockIdx.z;
    int r = (r_fixed < 0) ? (int)blockIdx.y : r_fixed;
    size_t sbase = (size_t)(b * R_ + r) * L_;
    const int2* recs = rec + sbase;
    const float* qb = q   + (size_t)b * L_ * D_;
    const float* vb = val + (size_t)b * L_ * D_;
    int loadv = (omode != 2);
    int h = tid & 3;
    int posq = c * 64 + (tid >> 2) * 4;           // first query of this lane's quad
    int2 rown = recs[posq + h];
    int own_w0 = rown.x;
    int own_bk = own_w0 & 0xFFFF0000;
    float m_own = 0.125f / __int_as_float(rown.y);   // == ||q_own||/8
    // wave query-bucket range (positions sorted by bucket -> first/last suffice)
    int minbk = __builtin_amdgcn_readfirstlane(recs[c * 64].x) & 0xFFFF0000;
    int maxbk = __builtin_amdgcn_readfirstlane(recs[c * 64 + 63].x) & 0xFFFF0000;
    int mls[4];
    #pragma unroll
    for (int qq = 0; qq < 4; ++qq) mls[qq] = recs[posq + qq].x & 0xFFFF;
    int ownpos = posq + h;
    v2f qv2[4][8];
    #pragma unroll
    for (int qq = 0; qq < 4; ++qq) {
        const float* qp = qb + (size_t)mls[qq] * D_ + h * 16;
        #pragma unroll
        for (int i = 0; i < 16; i += 4) {
            float4 f = *(const float4*)(qp + i);
            qv2[qq][i >> 1]       = (v2f){f.x, f.y};
            qv2[qq][(i >> 1) + 1] = (v2f){f.z, f.w};
        }
    }
    float ps[4] = {0.0f, 0.0f, 0.0f, 0.0f};
    v2f acc2[4][8];
    #pragma unroll
    for (int qq = 0; qq < 4; ++qq)
        #pragma unroll
        for (int i = 0; i < 8; ++i) acc2[qq][i] = (v2f){0.0f, 0.0f};

    #pragma unroll 1
    for (int s = 0; s < 8; ++s) {   // 8 stages of 16 keys: prev chunk (4) then current (4)
        int ck = ((c + NB_ - 1 + (s >> 2)) & (NB_ - 1)) * 64 + (s & 3) * 16;
        // stage-level skip: keys sorted within stage -> range test vs query buckets.
        // Dead stage contributes exactly 0 to ps/acc (expf(-1e9-m)==0.0f) -> exact.
        int sfir = __builtin_amdgcn_readfirstlane(recs[ck].x) & 0xFFFF0000;
        int slas = __builtin_amdgcn_readfirstlane(recs[ck + 15].x) & 0xFFFF0000;
        if (slas < minbk || sfir > maxbk) continue;
        {
            int rw = tid >> 2, cc = tid & 3;
            int rrec = recs[ck + rw].x;
            int rbk = rrec & 0xFFFF0000;
            if (rbk >= minbk && rbk <= maxbk) {   // predicated: dead rows never staged
                int kl = rrec & 0xFFFF;
                const float* kp = qb + (size_t)kl * D_ + cc * 16;
                float* kd = &kt[w][rw * 80 + cc * 20];
                #pragma unroll
                for (int i = 0; i < 16; i += 4) *(float4*)(kd + i) = *(const float4*)(kp + i);
                if (loadv) {
                    const float* vp = vb + (size_t)kl * D_ + cc * 16;
                    float* vd = &vt[w][rw * 80 + cc * 20];
                    #pragma unroll
                    for (int i = 0; i < 16; i += 4) *(float4*)(vd + i) = *(const float4*)(vp + i);
                }
            }
            if (tid < 16) krc[w][tid] = recs[ck + tid];
        }
        // no barrier: single-wave producer/consumer, lgkmcnt ordering suffices (R6)
        #pragma unroll
        for (int j = 0; j < 16; ++j) {
            int2 kv = krc[w][j];
            // per-key skip (uniform branch): bucket outside wave range -> exact zero
            int bkj = __builtin_amdgcn_readfirstlane(kv.x) & 0xFFFF0000;
            if (bkj < minbk || bkj > maxbk) continue;
            const float* kpj = &kt[w][j * 80 + h * 20];
            v2f a0 = (v2f){0.f, 0.f}, a1 = a0, a2 = a0, a3 = a0;
            #pragma unroll
            for (int i = 0; i < 16; i += 4) {
                float4 kk = *(const float4*)(kpj + i);
                v2f kA = (v2f){kk.x, kk.y}, kB = (v2f){kk.z, kk.w};
                int i2 = i >> 1;
                a0 = __builtin_elementwise_fma(qv2[0][i2], kA, a0);
                a0 = __builtin_elementwise_fma(qv2[0][i2 + 1], kB, a0);
                a1 = __builtin_elementwise_fma(qv2[1][i2], kA, a1);
                a1 = __builtin_elementwise_fma(qv2[1][i2 + 1], kB, a1);
                a2 = __builtin_elementwise_fma(qv2[2][i2], kA, a2);
                a2 = __builtin_elementwise_fma(qv2[2][i2 + 1], kB, a2);
                a3 = __builtin_elementwise_fma(qv2[3][i2], kA, a3);
                a3 = __builtin_elementwise_fma(qv2[3][i2 + 1], kB, a3);
            }
            float p0 = a0.x + a0.y, p1 = a1.x + a1.y, p2 = a2.x + a2.y, p3 = a3.x + a3.y;
            // 4x4 transpose-reduce across the quad: lane h ends with query h's full dot
            bool b0 = (h & 1), b1 = (h & 2) != 0;
            float u0 = b0 ? p1 : p0;
            float t0 = b0 ? p0 : p1;
            u0 += dpp_xor1(t0);
            float u2 = b0 ? p3 : p2;
            float t2 = b0 ? p2 : p3;
            u2 += dpp_xor1(t2);
            float dot = b1 ? u2 : u0;
            float t3 = b1 ? u0 : u2;
            dot += dpp_xor2(t3);
            float skr = __int_as_float(kv.y) * 0.125f;       // rn_k * 0.125
            float sc = dot * skr;
            sc = (own_bk == (kv.x & 0xFFFF0000)) ? sc : -1.0e9f;  // cross-bucket mask
            if (own_w0 == kv.x) sc = -1.0e5f;          // self mask (overrides, as in ref)
            float p = __expf(sc - m_own);              // static max: no rescaling ever
            ps[j & 3] += p;
            if (loadv) {
                v2f P0 = (v2f){quad_bcast0(p), quad_bcast0(p)};
                v2f P1 = (v2f){quad_bcast1(p), quad_bcast1(p)};
                v2f P2 = (v2f){quad_bcast2(p), quad_bcast2(p)};
                v2f P3 = (v2f){quad_bcast3(p), quad_bcast3(p)};
                const float* vpj = &vt[w][j * 80 + h * 20];
                float4 vv0 = *(const float4*)(vpj + 0);
                float4 vv1 = *(const float4*)(vpj + 4);
                float4 vv2 = *(const float4*)(vpj + 8);
                float4 vv3 = *(const float4*)(vpj + 12);
                v2f vAa = (v2f){vv0.x, vv0.y}, vAb = (v2f){vv0.z, vv0.w};
                v2f vAc = (v2f){vv1.x, vv1.y}, vAd = (v2f){vv1.z, vv1.w};
                v2f vAe = (v2f){vv2.x, vv2.y}, vAf = (v2f){vv2.z, vv2.w};
                v2f vAg = (v2f){vv3.x, vv3.y}, vAh = (v2f){vv3.z, vv3.w};
                acc2[0][0] = __builtin_elementwise_fma(P0, vAa, acc2[0][0]);
                acc2[0][1] = __builtin_elementwise_fma(P0, vAb, acc2[0][1]);
                acc2[0][2] = __builtin_elementwise_fma(P0, vAc, acc2[0][2]);
                acc2[0][3] = __builtin_elementwise_fma(P0, vAd, acc2[0][3]);
                acc2[0][4] = __builtin_elementwise_fma(P0, vAe, acc2[0][4]);
                acc2[0][5] = __builtin_elementwise_fma(P0, vAf, acc2[0][5]);
                acc2[0][6] = __builtin_elementwise_fma(P0, vAg, acc2[0][6]);
                acc2[0][7] = __builtin_elementwise_fma(P0, vAh, acc2[0][7]);
                acc2[1][0] = __builtin_elementwise_fma(P1, vAa, acc2[1][0]);
                acc2[1][1] = __builtin_elementwise_fma(P1, vAb, acc2[1][1]);
                acc2[1][2] = __builtin_elementwise_fma(P1, vAc, acc2[1][2]);
                acc2[1][3] = __builtin_elementwise_fma(P1, vAd, acc2[1][3]);
                acc2[1][4] = __builtin_elementwise_fma(P1, vAe, acc2[1][4]);
                acc2[1][5] = __builtin_elementwise_fma(P1, vAf, acc2[1][5]);
                acc2[1][6] = __builtin_elementwise_fma(P1, vAg, acc2[1][6]);
                acc2[1][7] = __builtin_elementwise_fma(P1, vAh, acc2[1][7]);
                acc2[2][0] = __builtin_elementwise_fma(P2, vAa, acc2[2][0]);
                acc2[2][1] = __builtin_elementwise_fma(P2, vAb, acc2[2][1]);
                acc2[2][2] = __builtin_elementwise_fma(P2, vAc, acc2[2][2]);
                acc2[2][3] = __builtin_elementwise_fma(P2, vAd, acc2[2][3]);
                acc2[2][4] = __builtin_elementwise_fma(P2, vAe, acc2[2][4]);
                acc2[2][5] = __builtin_elementwise_fma(P2, vAf, acc2[2][5]);
                acc2[2][6] = __builtin_elementwise_fma(P2, vAg, acc2[2][6]);
                acc2[2][7] = __builtin_elementwise_fma(P2, vAh, acc2[2][7]);
                acc2[3][0] = __builtin_elementwise_fma(P3, vAa, acc2[3][0]);
                acc2[3][1] = __builtin_elementwise_fma(P3, vAb, acc2[3][1]);
                acc2[3][2] = __builtin_elementwise_fma(P3, vAc, acc2[3][2]);
                acc2[3][3] = __builtin_elementwise_fma(P3, vAd, acc2[3][3]);
                acc2[3][4] = __builtin_elementwise_fma(P3, vAe, acc2[3][4]);
                acc2[3][5] = __builtin_elementwise_fma(P3, vAf, acc2[3][5]);
                acc2[3][6] = __builtin_elementwise_fma(P3, vAg, acc2[3][6]);
                acc2[3][7] = __builtin_elementwise_fma(P3, vAh, acc2[3][7]);
            }
        }
    }
    float sum = (ps[0] + ps[1]) + (ps[2] + ps[3]);
    float lse_own, inv_own;
    if (sum > 0.0f) { lse_own = m_own + logf(sum); inv_own = 1.0f / sum; }
    else            { lse_own = -3.0e38f;          inv_own = 0.0f; }   // fully-masked row
    if (omode != 3) lse[sbase + ownpos] = lse_own;
    if (omode == 0 || omode == 1) {
        float ivs[4];
        ivs[0] = quad_bcast0(inv_own); ivs[1] = quad_bcast1(inv_own);
        ivs[2] = quad_bcast2(inv_own); ivs[3] = quad_bcast3(inv_own);
        float* cbase = contrib + ((omode == 0) ? (size_t)(b * R_ + r) * L_ : (size_t)b * L_) * D_;
        #pragma unroll
        for (int qq = 0; qq < 4; ++qq) {
            float* cp = cbase + (size_t)(posq + qq) * D_ + h * 16;
            #pragma unroll
            for (int i = 0; i < 16; i += 4) {
                int i2 = i >> 1;
                float4 o;
                o.x = acc2[qq][i2].x * ivs[qq];     o.y = acc2[qq][i2].y * ivs[qq];
                o.z = acc2[qq][i2 + 1].x * ivs[qq]; o.w = acc2[qq][i2 + 1].y * ivs[qq];
                *(float4*)(cp + i) = o;
            }
        }
    } else if (omode == 3) {
        int brr = b * R_ + r;
        float gmv = gm[brr], gsv = gs[brr];
        float ls4[4], iv4[4];
        ls4[0] = quad_bcast0(lse_own); ls4[1] = quad_bcast1(lse_own);
        ls4[2] = quad_bcast2(lse_own); ls4[3] = quad_bcast3(lse_own);
        iv4[0] = quad_bcast0(inv_own); iv4[1] = quad_bcast1(inv_own);
        iv4[2] = quad_bcast2(inv_own); iv4[3] = quad_bcast3(inv_own);
        #pragma unroll
        for (int qq = 0; qq < 4; ++qq) {
            float wq = __expf(ls4[qq] - gmv) * gsv * iv4[qq];
            float* op = out + ((size_t)b * L_ + mls[qq]) * D_ + h * 16;
            #pragma unroll
            for (int i = 0; i < 8; ++i) {
                unsafeAtomicAdd(op + 2 * i,     wq * acc2[qq][i].x);
                unsafeAtomicAdd(op + 2 * i + 1, wq * acc2[qq][i].y);
            }
        }
    }
}

// ---------------- K5: softmax-over-L normalizers (max + fp64 sum) per (b,r)
__global__ __launch_bounds__(256) void k_wred(const float* __restrict__ lse, float* __restrict__ gm,
                                              float* __restrict__ gs, int r_w) {
    __shared__ float  sm[4];
    __shared__ double sd[4];
    int br = (r_w < 0) ? (int)blockIdx.x : ((int)blockIdx.x * R_ + r_w);
    const float* x = lse + (size_t)br * L_;
    int t = threadIdx.x;
    float mx = -3.0e38f;
    for (int i = t; i < L_; i += 256) mx = fmaxf(mx, x[i]);
    #pragma unroll
    for (int o = 32; o; o >>= 1) mx = fmaxf(mx, __shfl_down(mx, o));
    if ((t & 63) == 0) sm[t >> 6] = mx;
    __syncthreads();
    mx = fmaxf(fmaxf(sm[0], sm[1]), fmaxf(sm[2], sm[3]));
    double s = 0.0;
    for (int i = t; i < L_; i += 256) s += exp((double)x[i] - (double)mx);
    #pragma unroll
    for (int o = 32; o; o >>= 1) s += __shfl_down(s, o);
    if ((t & 63) == 0) sd[t >> 6] = s;
    __syncthreads();
    if (t == 0) { gm[br] = mx; gs[br] = (float)(1.0 / (sd[0] + sd[1] + sd[2] + sd[3])); }
}

// ---------------- K6a: gather all 4 rounds from full contrib, apply w, write out
__global__ __launch_bounds__(256) void k_comb_full(const float* __restrict__ contrib,
                                                   const int* __restrict__ iv,
                                                   const float* __restrict__ lse,
                                                   const float* __restrict__ gm,
                                                   const float* __restrict__ gs,
                                                   float* __restrict__ out) {
    int gid = blockIdx.x * 256 + threadIdx.x;
    int row = gid >> 2;              // b*L + l
    int ch  = (gid & 3) * 16;
    int b = row >> 13, l = row & (L_ - 1);
    float s[16];
    #pragma unroll
    for (int i = 0; i < 16; ++i) s[i] = 0.0f;
    #pragma unroll
    for (int r = 0; r < R_; ++r) {
        int brr = b * R_ + r;
        int pos = iv[(size_t)brr * L_ + l];
        float w = expf(lse[(size_t)brr * L_ + pos] - gm[brr]) * gs[brr];
        const float* cp = contrib + ((size_t)brr * L_ + pos) * D_ + ch;
        #pragma unroll
        for (int i = 0; i < 16; i += 4) {
            float4 f = *(const float4*)(cp + i);
            s[i]   = fmaf(w, f.x, s[i]);   s[i+1] = fmaf(w, f.y, s[i+1]);
            s[i+2] = fmaf(w, f.z, s[i+2]); s[i+3] = fmaf(w, f.w, s[i+3]);
        }
    }
    float* op = out + (size_t)row * D_ + ch;
    #pragma unroll
    for (int i = 0; i < 16; i += 4) {
        float4 o; o.x = s[i]; o.y = s[i+1]; o.z = s[i+2]; o.w = s[i+3];
        *(float4*)(op + i) = o;
    }
}

// ---------------- K6b: gather one round's slice, apply w, accumulate into out
__global__ __launch_bounds__(256) void k_comb_add(const float* __restrict__ contrib,
                                                  const int* __restrict__ iv,
                                                  const float* __restrict__ lse,
                                                  const float* __restrict__ gm,
                                                  const float* __restrict__ gs,
                                                  float* __restrict__ out, int r) {
    int gid = blockIdx.x * 256 + threadIdx.x;
    int row = gid >> 2;              // b*L + l
    int ch  = (gid & 3) * 16;
    int b = row >> 13, l = row & (L_ - 1);
    int brr = b * R_ + r;
    int pos = iv[(size_t)brr * L_ + l];
    float w = expf(lse[(size_t)brr * L_ + pos] - gm[brr]) * gs[brr];
    const float* cp = contrib + ((size_t)b * L_ + pos) * D_ + ch;
    float* op = out + (size_t)row * D_ + ch;
    #pragma unroll
    for (int i = 0; i < 16; i += 4) {
        float4 f = *(const float4*)(cp + i);
        float4 o = *(const float4*)(op + i);
        o.x = fmaf(w, f.x, o.x); o.y = fmaf(w, f.y, o.y);
        o.z = fmaf(w, f.z, o.z); o.w = fmaf(w, f.w, o.w);
        *(float4*)(op + i) = o;
    }
}

// ---------------- workspace layout (bytes)
// rec (int2, 4 MB) OVERLAYS rmn (fp64, 2 MB): rmn is dead after k_hash; rec is
// written by k_sort which runs after k_hash (stream-ordered).
// rmf (fp32, 1 MB) OVERLAYS iv (2 MB): rmf is dead after k_hash; iv is written
// by k_sort which runs after k_hash (stream-ordered).
#define OFF_RMN     0u           // double, 2 MB (k_rmnorm -> k_hash)
#define OFF_REC     0u           // int2,   4 MB (k_sort   -> k_flash), overlays RMN
#define OFF_RN      4194304u     // float,  512 KB
#define OFF_H       4718592u     // int,    2 MB
#define OFF_LSE     6815744u     // float,  2 MB
#define OFF_GM      8912896u
#define OFF_GS      8913152u
#define OFF_INV     8913408u     // int,    2 MB
#define OFF_RMF     8913408u     // float,  1 MB (k_rmnorm -> k_hash), overlays INV
#define OFF_CONTRIB 11010560u
#define CONTRIB_FULL_BYTES  134217728ull   // B*R*L*D*4 = 128 MiB
#define CONTRIB_SLICE_BYTES 33554432ull    // B*L*D*4   =  32 MiB

extern "C" void kernel_launch(void* const* d_in, const int* in_sizes, int n_in,
                              void* d_out, int out_size, void* d_ws, size_t ws_size,
                              hipStream_t stream) {
    const float* q  = (const float*)d_in[0];
    const float* v  = (const float*)d_in[1];
    const float* rm = (const float*)d_in[2];
    float* out = (float*)d_out;
    char* ws = (char*)d_ws;
    double* rmn = (double*)(ws + OFF_RMN);
    int2*   rec = (int2*)(ws + OFF_REC);
    float*  rn  = (float*)(ws + OFF_RN);
    int*    h   = (int*)(ws + OFF_H);
    float*  lse = (float*)(ws + OFF_LSE);
    float*  gm  = (float*)(ws + OFF_GM);
    float*  gs  = (float*)(ws + OFF_GS);
    int*    iv  = (int*)(ws + OFF_INV);
    float*  rmf = (float*)(ws + OFF_RMF);
    float*  contrib = (float*)(ws + OFF_CONTRIB);

    int tierA = (ws_size >= (size_t)OFF_CONTRIB + CONTRIB_FULL_BYTES) ? 1 : 0;
    int tierB = (!tierA && ws_size >= (size_t)OFF_CONTRIB + CONTRIB_SLICE_BYTES) ? 1 : 0;

    hipLaunchKernelGGL(k_rmnorm, dim3(B_ * R_), dim3(64), 0, stream, rm, rmn, rmf);
    hipLaunchKernelGGL(k_hash, dim3(L_ / 256, R_, B_), dim3(256), 0, stream, q, rmn, rmf, rn, h);
    hipLaunchKernelGGL(k_sort, dim3(B_ * R_), dim3(256), 0, stream, h, rn, iv, rec);

    if (tierA) {
        hipLaunchKernelGGL(k_flash, dim3(NB_ / 2, R_, B_), dim3(128), 0, stream, q, v, rec,
                           lse, gm, gs, out, contrib, -1, 0);
        hipLaunchKernelGGL(k_wred, dim3(B_ * R_), dim3(256), 0, stream, lse, gm, gs, -1);
        hipLaunchKernelGGL(k_comb_full, dim3(B_ * L_ * 4 / 256), dim3(256), 0, stream,
                           contrib, iv, lse, gm, gs, out);
    } else if (tierB) {
        hipMemsetAsync(d_out, 0, (size_t)B_ * L_ * D_ * sizeof(float), stream);
        for (int r = 0; r < R_; ++r) {
            hipLaunchKernelGGL(k_flash, dim3(NB_ / 2, 1, B_), dim3(128), 0, stream, q, v, rec,
                               lse, gm, gs, out, contrib, r, 1);
            hipLaunchKernelGGL(k_wred, dim3(B_), dim3(256), 0, stream, lse, gm, gs, r);
            hipLaunchKernelGGL(k_comb_add, dim3(B_ * L_ * 4 / 256), dim3(256), 0, stream,
                               contrib, iv, lse, gm, gs, out, r);
        }
    } else {
        // tier C: two flash passes (lse-only, then atomic w-weighted accumulate)
        hipMemsetAsync(d_out, 0, (size_t)B_ * L_ * D_ * sizeof(float), stream);
        hipLaunchKernelGGL(k_flash, dim3(NB_ / 2, R_, B_), dim3(128), 0, stream, q, v, rec,
                           lse, gm, gs, out, contrib, -1, 2);
        hipLaunchKernelGGL(k_wred, dim3(B_ * R_), dim3(256), 0, stream, lse, gm, gs, -1);
        hipLaunchKernelGGL(k_flash, dim3(NB_ / 2, R_, B_), dim3(128), 0, stream, q, v, rec,
                           lse, gm, gs, out, contrib, -1, 3);
    }
}